// Round 1
// baseline (10293.614 us; speedup 1.0000x reference)
//
#include <hip/hip_runtime.h>
#include <math.h>

#define NB 2
#define NH 16
#define NT 2048
#define ND 64
#define NC 1024

// ---------------------------------------------------------------------------
// Kernel 1: y = x(4096x1024) @ w(1024x1024), output scattered to [B,H,T,d]
// 64x64 tile, 256 threads, 4x4 micro-tile, K-step 16.
// ---------------------------------------------------------------------------
__global__ __launch_bounds__(256) void qkv_gemm(const float* __restrict__ x,
                                                const float* __restrict__ w,
                                                float* __restrict__ dst) {
    __shared__ float As[64][17];  // [m][k], +1 pad
    __shared__ float Bs[16][65];  // [k][n], +1 pad
    const int tid = threadIdx.x;
    const int tx = tid & 15, ty = tid >> 4;
    const int m0 = blockIdx.x * 64;
    const int n0 = blockIdx.y * 64;

    float acc[4][4] = {};

    for (int kk = 0; kk < NC; kk += 16) {
        // A tile: 64 rows x 16 k
        for (int e = tid; e < 1024; e += 256) {
            int i = e >> 4, j = e & 15;
            As[i][j] = x[(size_t)(m0 + i) * NC + kk + j];
        }
        // B tile: 16 k x 64 cols
        for (int e = tid; e < 1024; e += 256) {
            int j = e >> 6, i = e & 63;
            Bs[j][i] = w[(size_t)(kk + j) * NC + n0 + i];
        }
        __syncthreads();
        #pragma unroll
        for (int j = 0; j < 16; ++j) {
            float a[4], b[4];
            #pragma unroll
            for (int r = 0; r < 4; ++r) a[r] = As[ty * 4 + r][j];
            #pragma unroll
            for (int c = 0; c < 4; ++c) b[c] = Bs[j][tx * 4 + c];
            #pragma unroll
            for (int r = 0; r < 4; ++r)
                #pragma unroll
                for (int c = 0; c < 4; ++c)
                    acc[r][c] += a[r] * b[c];
        }
        __syncthreads();
    }

    // scatter to [ (b*NH + h) * NT + t ] * ND + dd
    #pragma unroll
    for (int r = 0; r < 4; ++r) {
        int m = m0 + ty * 4 + r;
        int bb = m / NT, tt = m % NT;
        #pragma unroll
        for (int c = 0; c < 4; ++c) {
            int n = n0 + tx * 4 + c;
            int hh = n >> 6, dd = n & 63;
            dst[(((size_t)bb * NH + hh) * NT + tt) * ND + dd] = acc[r][c];
        }
    }
}

// ---------------------------------------------------------------------------
// Kernel 2: per key-column k: m_k = max_{q>=k} score(q,k), sinv_k = 1/sum exp
// score(q,k) = (Q[q].K[k]) * 0.125 + (k - q) * slope_h
// One wave per column; lane = d index.
// ---------------------------------------------------------------------------
__global__ __launch_bounds__(256) void colstats(const float* __restrict__ Q,
                                                const float* __restrict__ K,
                                                float* __restrict__ colM,
                                                float* __restrict__ colSinv) {
    const int lane = threadIdx.x & 63;
    const int wave = threadIdx.x >> 6;
    const int ci = blockIdx.x * 4 + wave;   // global column index = bh*NT + k
    const int k = ci & (NT - 1);
    const int bh = ci >> 11;                // NT = 2048
    const int h = bh & (NH - 1);
    const float slope = exp2f(-0.5f * (float)(h + 1));

    const float kv = K[(size_t)ci * ND + lane];
    const float* Qbase = Q + (size_t)bh * NT * ND;

    float m = -INFINITY, s = 0.f;
    for (int q = k; q < NT; ++q) {
        float v = Qbase[(size_t)q * ND + lane] * kv;
        #pragma unroll
        for (int off = 32; off; off >>= 1) v += __shfl_xor(v, off);
        v = v * 0.125f + (float)(k - q) * slope;
        if (v > m) { s *= expf(m - v); m = v; }
        s += expf(v - m);
    }
    if (lane == 0) {
        colM[ci] = m;
        colSinv[ci] = 1.f / s;
    }
}

// ---------------------------------------------------------------------------
// Kernel 3: per query row q: Att[bh,q,:] = sum_{k<=q} exp(score-m_k)*sinv_k * V[k,:]
// One wave per row; lane = d index. Q row held in register.
// ---------------------------------------------------------------------------
__global__ __launch_bounds__(256) void pv(const float* __restrict__ Q,
                                          const float* __restrict__ K,
                                          const float* __restrict__ V,
                                          const float* __restrict__ colM,
                                          const float* __restrict__ colSinv,
                                          float* __restrict__ att) {
    const int lane = threadIdx.x & 63;
    const int wave = threadIdx.x >> 6;
    const int ri = blockIdx.x * 4 + wave;   // = bh*NT + q
    const int q = ri & (NT - 1);
    const int bh = ri >> 11;
    const int h = bh & (NH - 1);
    const float slope = exp2f(-0.5f * (float)(h + 1));

    const float qv = Q[(size_t)ri * ND + lane];
    const float* Kbase = K + (size_t)bh * NT * ND;
    const float* Vbase = V + (size_t)bh * NT * ND;
    const float* cM = colM + (size_t)bh * NT;
    const float* cS = colSinv + (size_t)bh * NT;

    float acc = 0.f;
    for (int k = 0; k <= q; ++k) {
        float v = Kbase[(size_t)k * ND + lane] * qv;
        #pragma unroll
        for (int off = 32; off; off >>= 1) v += __shfl_xor(v, off);
        float p = expf(v * 0.125f + (float)(k - q) * slope - cM[k]) * cS[k];
        acc += p * Vbase[(size_t)k * ND + lane];
    }
    att[(size_t)ri * ND + lane] = acc;
}

// ---------------------------------------------------------------------------
// Kernel 4: out[row, c] = x[row, c] + sum_dd ( sum_h Att[b,h,t,dd] ) * wo[dd, c]
// One block (256 thr) per row (b*NT + t).
// ---------------------------------------------------------------------------
__global__ __launch_bounds__(256) void out_proj(const float* __restrict__ x,
                                                const float* __restrict__ att,
                                                const float* __restrict__ wo,
                                                float* __restrict__ out) {
    __shared__ float as[ND];
    const int row = blockIdx.x;            // b*NT + t
    const int tid = threadIdx.x;
    const int bb = row >> 11, tt = row & (NT - 1);

    if (tid < ND) {
        float s = 0.f;
        #pragma unroll
        for (int h = 0; h < NH; ++h)
            s += att[(((size_t)bb * NH + h) * NT + tt) * ND + tid];
        as[tid] = s;
    }
    __syncthreads();

    for (int c = tid; c < NC; c += 256) {
        float acc = 0.f;
        #pragma unroll
        for (int dd = 0; dd < ND; ++dd)
            acc += as[dd] * wo[(size_t)dd * NC + c];
        out[(size_t)row * NC + c] = x[(size_t)row * NC + c] + acc;
    }
}

// ---------------------------------------------------------------------------
extern "C" void kernel_launch(void* const* d_in, const int* in_sizes, int n_in,
                              void* d_out, int out_size, void* d_ws, size_t ws_size,
                              hipStream_t stream) {
    const float* x  = (const float*)d_in[0];
    const float* wq = (const float*)d_in[1];
    const float* wk = (const float*)d_in[2];
    const float* wv = (const float*)d_in[3];
    const float* wo = (const float*)d_in[4];
    float* out = (float*)d_out;

    const size_t qkv_elems = (size_t)NB * NH * NT * ND;   // 4,194,304
    float* ws = (float*)d_ws;
    float* Q    = ws;
    float* K    = Q + qkv_elems;
    float* V    = K + qkv_elems;
    float* att  = V + qkv_elems;
    float* colM = att + qkv_elems;
    float* colS = colM + (size_t)NB * NH * NT;
    // total: 4*16MB + 0.5MB ~= 64.5MB of d_ws

    dim3 gemm_grid(64, 16);  // M/64=64, N/64=16
    qkv_gemm<<<gemm_grid, 256, 0, stream>>>(x, wq, Q);
    qkv_gemm<<<gemm_grid, 256, 0, stream>>>(x, wk, K);
    qkv_gemm<<<gemm_grid, 256, 0, stream>>>(x, wv, V);

    const int ncols = NB * NH * NT;          // 65536
    colstats<<<ncols / 4, 256, 0, stream>>>(Q, K, colM, colS);
    pv<<<ncols / 4, 256, 0, stream>>>(Q, K, V, colM, colS, att);

    out_proj<<<NB * NT, 256, 0, stream>>>(x, att, wo, out);
}

// Round 2
// 565.105 us; speedup vs baseline: 18.2154x; 18.2154x over previous
//
#include <hip/hip_runtime.h>
#include <math.h>

#define NB 2
#define NH 16
#define NT 2048
#define ND 64
#define NC 1024
#define L2E 1.44269504f

typedef __attribute__((ext_vector_type(4))) float f32x4;
typedef __attribute__((ext_vector_type(8))) short short8;
typedef __attribute__((ext_vector_type(4))) short short4_t;
typedef __attribute__((ext_vector_type(8))) unsigned short ushort8;
typedef __attribute__((ext_vector_type(4))) unsigned short ushort4_t;

__device__ __forceinline__ unsigned short f2bf(float f) {
    unsigned u = __builtin_bit_cast(unsigned, f);
    unsigned r = (u + 0x7FFFu + ((u >> 16) & 1u)) >> 16;
    return (unsigned short)r;
}

// load a bf16 A/B fragment with the lane->k bijection g(gq,i)=4*gq+(i&3)+16*(i>>2)+32*half
__device__ __forceinline__ short8 frag_load(const unsigned short* rowp, int g, int half) {
    short8 v;
    short4_t lo = *(const short4_t*)(rowp + 4 * g + 32 * half);
    short4_t hi = *(const short4_t*)(rowp + 4 * g + 16 + 32 * half);
    #pragma unroll
    for (int j = 0; j < 4; ++j) { v[j] = lo[j]; v[4 + j] = hi[j]; }
    return v;
}

// ---------------------------------------------------------------------------
// f32 -> bf16 convert (vectorized x4)
// ---------------------------------------------------------------------------
__global__ __launch_bounds__(256) void cvt_bf16(const float* __restrict__ src,
                                                unsigned short* __restrict__ dst, int n4) {
    int i = blockIdx.x * 256 + threadIdx.x;
    if (i >= n4) return;
    f32x4 v = ((const f32x4*)src)[i];
    ushort4_t o;
    #pragma unroll
    for (int j = 0; j < 4; ++j) o[j] = f2bf(v[j]);
    ((ushort4_t*)dst)[i] = o;
}

// ---------------------------------------------------------------------------
// bf16 MFMA GEMM: Y[4096x1024] = Xh[4096x1024] @ W[1024x1024],
// output scattered bf16 to [bh][t][d]. 64x64 tile, 4 waves, K-step 64.
// ---------------------------------------------------------------------------
__global__ __launch_bounds__(256) void gemm_qkv(const unsigned short* __restrict__ Xh,
                                                const unsigned short* __restrict__ W,
                                                unsigned short* __restrict__ dst) {
    __shared__ __align__(16) unsigned short Xs[64][72];
    __shared__ __align__(16) unsigned short Ws[64][72];  // transposed tile: [n][k]
    const int tid = threadIdx.x;
    const int lane = tid & 63, w = tid >> 6;
    const int g = lane >> 4, l15 = lane & 15;
    const int m0 = blockIdx.x * 64, n0 = blockIdx.y * 64;
    const int srow = tid >> 2, scol = (tid & 3) * 16;

    f32x4 acc[4] = {};

    for (int kk = 0; kk < NC; kk += 64) {
        {   // stage X tile (row-major)
            const unsigned short* p = Xh + (size_t)(m0 + srow) * NC + kk + scol;
            *(ushort8*)&Xs[srow][scol]     = *(const ushort8*)p;
            *(ushort8*)&Xs[srow][scol + 8] = *(const ushort8*)(p + 8);
        }
        {   // stage W tile transposed
            int r = tid & 63;
            #pragma unroll
            for (int i = 0; i < 2; ++i) {
                int chunk = (tid >> 6) + 4 * i;
                ushort8 v = *(const ushort8*)(W + (size_t)(kk + r) * NC + n0 + 8 * chunk);
                #pragma unroll
                for (int j = 0; j < 8; ++j) Ws[8 * chunk + j][r] = v[j];
            }
        }
        __syncthreads();
        short8 af[2];
        #pragma unroll
        for (int h = 0; h < 2; ++h) af[h] = frag_load(&Xs[16 * w + l15][0], g, h);
        #pragma unroll
        for (int ns = 0; ns < 4; ++ns) {
            #pragma unroll
            for (int h = 0; h < 2; ++h) {
                short8 bf = frag_load(&Ws[16 * ns + l15][0], g, h);
                acc[ns] = __builtin_amdgcn_mfma_f32_16x16x32_bf16(af[h], bf, acc[ns], 0, 0, 0);
            }
        }
        __syncthreads();
    }
    #pragma unroll
    for (int ns = 0; ns < 4; ++ns) {
        #pragma unroll
        for (int r = 0; r < 4; ++r) {
            int m = m0 + 16 * w + 4 * g + r;
            int n = n0 + 16 * ns + l15;
            int bb = m >> 11, tt = m & (NT - 1);
            int hh = n >> 6, dd = n & 63;
            dst[(((size_t)bb * NH + hh) * NT + tt) * ND + dd] = f2bf(acc[ns][r]);
        }
    }
}

// ---------------------------------------------------------------------------
// Vh [bh][t][d] -> Vt [bh][d][t]  (tiled transpose, bf16)
// ---------------------------------------------------------------------------
__global__ __launch_bounds__(256) void transpose_v(const unsigned short* __restrict__ Vh,
                                                   unsigned short* __restrict__ Vt) {
    __shared__ __align__(16) unsigned short T[64][72];
    const int tid = threadIdx.x;
    const int bh = blockIdx.y;
    const int t0 = blockIdx.x * 64;
    const int srow = tid >> 2, scol = (tid & 3) * 16;
    const unsigned short* p = Vh + ((size_t)bh * NT + t0 + srow) * ND + scol;
    *(ushort8*)&T[srow][scol]     = *(const ushort8*)p;
    *(ushort8*)&T[srow][scol + 8] = *(const ushort8*)(p + 8);
    __syncthreads();
    ushort8 o0, o1;
    #pragma unroll
    for (int j = 0; j < 8; ++j) { o0[j] = T[scol + j][srow]; o1[j] = T[scol + 8 + j][srow]; }
    unsigned short* q = Vt + ((size_t)bh * ND + srow) * NT + t0 + scol;
    *(ushort8*)q       = o0;
    *(ushort8*)(q + 8) = o1;
}

// ---------------------------------------------------------------------------
// Pass A: per key k, over q in [k,T): L[k] = max_q t + log2(sum_q exp2(t - max))
// t = (Q.K)*0.125*L2E + (k-q)*slope*L2E.  D[key,q] via mfma(K,Q); online stats
// per lane (4 keys x its q column), final xor-reduce over 16 q-lanes.
// ---------------------------------------------------------------------------
__global__ __launch_bounds__(256) void colstats(const unsigned short* __restrict__ Qh,
                                                const unsigned short* __restrict__ Kh,
                                                float* __restrict__ Lout) {
    const int tid = threadIdx.x;
    const int lane = tid & 63, w = tid >> 6;
    const int g = lane >> 4, l15 = lane & 15;
    const int kt = blockIdx.x, bh = blockIdx.y;
    const int K0 = kt * 64;
    const int hh = bh & (NH - 1);
    const float slL2 = exp2f(-0.5f * (float)(hh + 1)) * L2E;
    const float C1 = 0.125f * L2E;

    short8 ak[2];
    {
        const unsigned short* kr = Kh + ((size_t)bh * NT + K0 + 16 * w + l15) * ND;
        #pragma unroll
        for (int h = 0; h < 2; ++h) ak[h] = frag_load(kr, g, h);
    }
    int kidx[4];
    float m[4], s[4];
    #pragma unroll
    for (int r = 0; r < 4; ++r) { kidx[r] = K0 + 16 * w + 4 * g + r; m[r] = -1e30f; s[r] = 0.f; }

    for (int q0 = K0; q0 < NT; q0 += 16) {
        const unsigned short* qr = Qh + ((size_t)bh * NT + q0 + l15) * ND;
        short8 bq0 = frag_load(qr, g, 0);
        short8 bq1 = frag_load(qr, g, 1);
        f32x4 d = {};
        d = __builtin_amdgcn_mfma_f32_16x16x32_bf16(ak[0], bq0, d, 0, 0, 0);
        d = __builtin_amdgcn_mfma_f32_16x16x32_bf16(ak[1], bq1, d, 0, 0, 0);
        const int q = q0 + l15;
        #pragma unroll
        for (int r = 0; r < 4; ++r) {
            float t = (q >= kidx[r]) ? fmaf(d[r], C1, (float)(kidx[r] - q) * slL2) : -1e30f;
            float mn = fmaxf(m[r], t);
            s[r] = s[r] * exp2f(m[r] - mn) + exp2f(t - mn);
            m[r] = mn;
        }
    }
    #pragma unroll
    for (int off = 1; off <= 8; off <<= 1) {
        #pragma unroll
        for (int r = 0; r < 4; ++r) {
            float mo = __shfl_xor(m[r], off);
            float so = __shfl_xor(s[r], off);
            float mn = fmaxf(m[r], mo);
            s[r] = s[r] * exp2f(m[r] - mn) + so * exp2f(mo - mn);
            m[r] = mn;
        }
    }
    if (l15 == 0) {
        #pragma unroll
        for (int r = 0; r < 4; ++r)
            Lout[(size_t)bh * NT + kidx[r]] = m[r] + log2f(s[r]);
    }
}

// ---------------------------------------------------------------------------
// Pass B: per 64-q block, loop k-tiles <= qt:
//   S^T strip via mfma(K,Q)  -> lane holds P row for its q (16 k-values)
//   p = exp2(t - L[k]) in-register, pack bf16 -> PV mfma A-operand directly.
// ---------------------------------------------------------------------------
__global__ __launch_bounds__(256) void attn_pv(const unsigned short* __restrict__ Qh,
                                               const unsigned short* __restrict__ Kh,
                                               const unsigned short* __restrict__ Vt,
                                               const float* __restrict__ Lc,
                                               float* __restrict__ att) {
    __shared__ __align__(16) unsigned short Ks[64][72];
    __shared__ __align__(16) unsigned short Vs[64][72];   // [d][k]
    __shared__ __align__(16) float Ls[64];
    const int tid = threadIdx.x;
    const int lane = tid & 63, w = tid >> 6;
    const int g = lane >> 4, l15 = lane & 15;
    const int qt = blockIdx.x, bh = blockIdx.y;
    const int Q0 = qt * 64;
    const int hh = bh & (NH - 1);
    const float slL2 = exp2f(-0.5f * (float)(hh + 1)) * L2E;
    const float C1 = 0.125f * L2E;
    const int Qs = Q0 + 16 * w;
    const int q = Qs + l15;
    const int srow = tid >> 2, scol = (tid & 3) * 16;

    short8 bq[2];
    {
        const unsigned short* qr = Qh + ((size_t)bh * NT + q) * ND;
        #pragma unroll
        for (int h = 0; h < 2; ++h) bq[h] = frag_load(qr, g, h);
    }
    f32x4 o[4] = {};

    for (int ks = 0; ks <= qt; ++ks) {
        const int K0 = ks * 64;
        {
            const unsigned short* kp = Kh + ((size_t)bh * NT + K0 + srow) * ND + scol;
            *(ushort8*)&Ks[srow][scol]     = *(const ushort8*)kp;
            *(ushort8*)&Ks[srow][scol + 8] = *(const ushort8*)(kp + 8);
            const unsigned short* vp = Vt + ((size_t)bh * ND + srow) * NT + K0 + scol;
            *(ushort8*)&Vs[srow][scol]     = *(const ushort8*)vp;
            *(ushort8*)&Vs[srow][scol + 8] = *(const ushort8*)(vp + 8);
            if (tid < 64) Ls[tid] = Lc[(size_t)bh * NT + K0 + tid];
        }
        __syncthreads();

        f32x4 pacc[4];
        #pragma unroll
        for (int s4 = 0; s4 < 4; ++s4) {
            const unsigned short* kr = &Ks[16 * s4 + l15][0];
            f32x4 d = {};
            #pragma unroll
            for (int h = 0; h < 2; ++h) {
                short8 a = frag_load(kr, g, h);
                d = __builtin_amdgcn_mfma_f32_16x16x32_bf16(a, bq[h], d, 0, 0, 0);
            }
            pacc[s4] = d;
        }

        short8 pa[2];
        const bool diag = (ks == qt);
        #pragma unroll
        for (int s4 = 0; s4 < 4; ++s4) {
            f32x4 Lf = *(const f32x4*)&Ls[16 * s4 + 4 * g];
            #pragma unroll
            for (int r = 0; r < 4; ++r) {
                int k = K0 + 16 * s4 + 4 * g + r;
                float c = fmaf((float)(k - q), slL2, -Lf[r]);
                float t = fmaf(pacc[s4][r], C1, c);
                float p = exp2f(t);
                if (diag && (k > q)) p = 0.f;
                pa[s4 >> 1][4 * (s4 & 1) + r] = (short)f2bf(p);
            }
        }

        #pragma unroll
        for (int n = 0; n < 4; ++n) {
            const unsigned short* vr = &Vs[16 * n + l15][0];
            #pragma unroll
            for (int h = 0; h < 2; ++h) {
                short8 b = frag_load(vr, g, h);
                o[n] = __builtin_amdgcn_mfma_f32_16x16x32_bf16(pa[h], b, o[n], 0, 0, 0);
            }
        }
        __syncthreads();
    }
    #pragma unroll
    for (int n = 0; n < 4; ++n)
        #pragma unroll
        for (int r = 0; r < 4; ++r)
            att[((size_t)bh * NT + Qs + 4 * g + r) * ND + 16 * n + l15] = o[n][r];
}

// ---------------------------------------------------------------------------
// out[row,c] = x[row,c] + (sum_h att[b,h,t,:]) @ wo
// ---------------------------------------------------------------------------
__global__ __launch_bounds__(256) void out_proj(const float* __restrict__ x,
                                                const float* __restrict__ att,
                                                const float* __restrict__ wo,
                                                float* __restrict__ out) {
    __shared__ float as[ND];
    const int row = blockIdx.x;
    const int tid = threadIdx.x;
    const int bb = row >> 11, tt = row & (NT - 1);

    if (tid < ND) {
        float s = 0.f;
        #pragma unroll
        for (int h = 0; h < NH; ++h)
            s += att[(((size_t)bb * NH + h) * NT + tt) * ND + tid];
        as[tid] = s;
    }
    __syncthreads();

    for (int c = tid; c < NC; c += 256) {
        float acc = 0.f;
        #pragma unroll
        for (int dd = 0; dd < ND; ++dd)
            acc += as[dd] * wo[(size_t)dd * NC + c];
        out[(size_t)row * NC + c] = x[(size_t)row * NC + c] + acc;
    }
}

// ---------------------------------------------------------------------------
extern "C" void kernel_launch(void* const* d_in, const int* in_sizes, int n_in,
                              void* d_out, int out_size, void* d_ws, size_t ws_size,
                              hipStream_t stream) {
    const float* x  = (const float*)d_in[0];
    const float* wq = (const float*)d_in[1];
    const float* wk = (const float*)d_in[2];
    const float* wv = (const float*)d_in[3];
    const float* wo = (const float*)d_in[4];
    float* out = (float*)d_out;

    const size_t MB = 1u << 20;
    unsigned char* w8 = (unsigned char*)d_ws;
    unsigned short* Xh  = (unsigned short*)(w8);            //  8 MB (4096x1024)
    unsigned short* Whq = (unsigned short*)(w8 + 8 * MB);   //  2 MB
    unsigned short* Whk = (unsigned short*)(w8 + 10 * MB);  //  2 MB
    unsigned short* Whv = (unsigned short*)(w8 + 12 * MB);  //  2 MB
    unsigned short* Qh  = (unsigned short*)(w8 + 14 * MB);  //  8 MB
    unsigned short* Kh  = (unsigned short*)(w8 + 22 * MB);  //  8 MB
    unsigned short* Vh  = (unsigned short*)(w8 + 30 * MB);  //  8 MB
    unsigned short* Vt  = (unsigned short*)(w8 + 38 * MB);  //  8 MB
    float*          Lc  = (float*)(w8 + 46 * MB);           //  0.25 MB
    float*          att = (float*)(w8 + 47 * MB);           // 16 MB

    cvt_bf16<<<(NB * NT * NC) / 1024, 256, 0, stream>>>(x,  Xh,  (NB * NT * NC) / 4);
    cvt_bf16<<<(NC * NC) / 1024, 256, 0, stream>>>(wq, Whq, (NC * NC) / 4);
    cvt_bf16<<<(NC * NC) / 1024, 256, 0, stream>>>(wk, Whk, (NC * NC) / 4);
    cvt_bf16<<<(NC * NC) / 1024, 256, 0, stream>>>(wv, Whv, (NC * NC) / 4);

    dim3 ggrid(64, 16);
    gemm_qkv<<<ggrid, 256, 0, stream>>>(Xh, Whq, Qh);
    gemm_qkv<<<ggrid, 256, 0, stream>>>(Xh, Whk, Kh);
    gemm_qkv<<<ggrid, 256, 0, stream>>>(Xh, Whv, Vh);

    transpose_v<<<dim3(32, 32), 256, 0, stream>>>(Vh, Vt);

    colstats<<<dim3(32, 32), 256, 0, stream>>>(Qh, Kh, Lc);
    attn_pv<<<dim3(32, 32), 256, 0, stream>>>(Qh, Kh, Vt, Lc, att);

    out_proj<<<NB * NT, 256, 0, stream>>>(x, att, wo, out);
}